// Round 20
// baseline (181.606 us; speedup 1.0000x reference)
//
#include <hip/hip_runtime.h>
#include <hip/hip_fp16.h>
#include <cstddef>

static constexpr int TPB = 256;
// bucket = 256 consecutive dst nodes (shift 8); NBKT = ceil(N/256) <= 512
static constexpr int MAXBKT = 512;
// fixed pairs region per bucket; mean bucket load = 8192, sigma ~ 90 -> 16000 is ~86 sigma
static constexpr int BKT_CAP = 16000;
static constexpr int P_TPB = 512;            // partition: 512 thr x 512 blocks = 2 blk/CU
static constexpr int B_TPB = 1024;           // bucket_build: 1024 thr, ~1.5 blk/CU

// single pass: partition edges into fixed per-bucket regions; per-(block,bucket)
// private contiguous sub-ranges via one global atomic per bucket. entry=(s<<8)|(d&255).
__global__ __launch_bounds__(P_TPB) void k_partition(const int* __restrict__ src,
                                                     const int* __restrict__ dst,
                                                     int* __restrict__ pair_cur,
                                                     int* __restrict__ pairs, int E, int nbkt) {
    __shared__ int hist[MAXBKT];
    __shared__ int base[MAXBKT];
    const int chunk = (E + gridDim.x - 1) / gridDim.x;
    const int e0 = blockIdx.x * chunk;
    const int e1 = min(e0 + chunk, E);
    for (int b = threadIdx.x; b < nbkt; b += P_TPB) hist[b] = 0;
    __syncthreads();
    for (int e = e0 + threadIdx.x; e < e1; e += P_TPB)
        atomicAdd(&hist[dst[e] >> 8], 1);
    __syncthreads();
    for (int b = threadIdx.x; b < nbkt; b += P_TPB) {
        int h = hist[b];
        base[b] = b * BKT_CAP + (h ? atomicAdd(&pair_cur[b], h) : 0);
    }
    __syncthreads();
    for (int e = e0 + threadIdx.x; e < e1; e += P_TPB) {
        int s = src[e], d = dst[e];
        int slot = atomicAdd(&base[d >> 8], 1);
        pairs[slot] = (s << 8) | (d & 255);    // s < 2^17 -> fits
    }
}

// fused CSR build: one block per bucket. LDS hist -> cnt/dinv; padded local scan;
// global base via atomic allocator (layout nondeterminism does not change outputs);
// LDS-cursor scatter; pad slots filled with dummy index N (zero row) so the gather
// loop needs no tail. Pairs region read twice (2nd read L2-hot).
__global__ __launch_bounds__(B_TPB) void k_bucket_build(const int* __restrict__ pair_cur,
                                                        const int* __restrict__ pairs,
                                                        int* __restrict__ alloc,
                                                        int* __restrict__ cnt,
                                                        int* __restrict__ row_start,
                                                        float* __restrict__ dinv,
                                                        int* __restrict__ csr, int N) {
    __shared__ int c[256];
    __shared__ int cur[256];
    __shared__ int wsum[4];
    __shared__ int base_s;
    int b = blockIdx.x;
    int tid = threadIdx.x;
    int lo = b * BKT_CAP, hi = lo + pair_cur[b];
    if (tid < 256) c[tid] = 0;
    __syncthreads();
    for (int k = lo + tid; k < hi; k += B_TPB)
        atomicAdd(&c[pairs[k] & 255], 1);
    __syncthreads();
    int node = (b << 8) + tid;
    int cc = 0, p = 0, excl = 0;
    if (tid < 256) {
        cc = c[tid];
        p = (node < N) ? ((cc + 15) & ~15) : 0;
        int lane = tid & 63, w = tid >> 6;
        int v = p;
        #pragma unroll
        for (int off = 1; off < 64; off <<= 1) {
            int u = __shfl_up(v, off);
            if (lane >= off) v += u;
        }
        if (lane == 63) wsum[w] = v;
        excl = v - p;                        // within-wave exclusive (add woff later)
    }
    __syncthreads();
    if (tid == 0) {
        int total = wsum[0] + wsum[1] + wsum[2] + wsum[3];
        base_s = atomicAdd(alloc, total);
    }
    __syncthreads();
    if (tid < 256 && node < N) {
        int w = tid >> 6;
        int woff = 0;
        for (int i = 0; i < w; ++i) woff += wsum[i];
        int rs = base_s + woff + excl;
        row_start[node] = rs;
        cnt[node] = cc;
        dinv[node] = rsqrtf(1.0f + (float)cc);   // deg = cnt + 1 (self-loop)
        cur[tid] = rs;
    }
    __syncthreads();
    for (int k = lo + tid; k < hi; k += B_TPB) {
        int pp = pairs[k];
        int slot = atomicAdd(&cur[pp & 255], 1);
        csr[slot] = pp >> 8;
    }
    __syncthreads();
    if (tid < 256 && node < N) {             // fill pad slots with dummy index N
        int end = row_start[node] + ((cc + 15) & ~15);
        for (int j = cur[tid]; j < end; ++j) csr[j] = N;
    }
}

// -------------------- h1h = fp16( dinv * (x @ W1) )   [N,128]x[128,64], row-scaled
// quarter-wave per row: lane&15 selects 4 consecutive features, lane>>4 selects row in quad.
// Block 0 also zeroes the dummy row N -- AFTER pairs (which aliases h1h) was consumed
// by k_bucket_build, and before k_gather1 reads it (stream order).
__global__ __launch_bounds__(TPB) void k_gemm1(const float* __restrict__ x,
                                               const float* __restrict__ W1,
                                               const float* __restrict__ dinv,
                                               __half* __restrict__ h1h, int N) {
    if (blockIdx.x == 0 && threadIdx.x < 32)
        reinterpret_cast<int*>(h1h)[(size_t)N * 32 + threadIdx.x] = 0;
    __shared__ float W1s[128 * 64];          // 32 KB
    {
        const float4* W1v = reinterpret_cast<const float4*>(W1);
        float4* W1sv = reinterpret_cast<float4*>(W1s);
        for (int i = threadIdx.x; i < 128 * 64 / 4; i += TPB) W1sv[i] = W1v[i];
    }
    __syncthreads();
    const int lane = threadIdx.x & 63;
    const int wid  = threadIdx.x >> 6;       // 4 waves
    const int q    = lane >> 4;              // row within quad
    const int f4   = (lane & 15) * 4;        // feature base
    for (int rb = blockIdx.x * 16 + wid * 4; rb < N; rb += gridDim.x * 16) {
        int row = rb + q;
        const float4* xr4 = reinterpret_cast<const float4*>(x + (size_t)row * 128);
        float dn = dinv[row];
        float ax = 0.f, ay = 0.f, az = 0.f, aw = 0.f;
        #pragma unroll 8
        for (int k4 = 0; k4 < 32; ++k4) {
            float4 xv = xr4[k4];             // quarter-uniform broadcast load
            const float4* wrow = reinterpret_cast<const float4*>(&W1s[(k4 * 4) * 64 + f4]);
            float4 w0 = wrow[0];
            float4 w1 = wrow[16];            // next k: +64 floats = +16 float4
            float4 w2 = wrow[32];
            float4 w3 = wrow[48];
            ax = fmaf(xv.x, w0.x, ax); ay = fmaf(xv.x, w0.y, ay);
            az = fmaf(xv.x, w0.z, az); aw = fmaf(xv.x, w0.w, aw);
            ax = fmaf(xv.y, w1.x, ax); ay = fmaf(xv.y, w1.y, ay);
            az = fmaf(xv.y, w1.z, az); aw = fmaf(xv.y, w1.w, aw);
            ax = fmaf(xv.z, w2.x, ax); ay = fmaf(xv.z, w2.y, ay);
            az = fmaf(xv.z, w2.z, az); aw = fmaf(xv.z, w2.w, aw);
            ax = fmaf(xv.w, w3.x, ax); ay = fmaf(xv.w, w3.y, ay);
            az = fmaf(xv.w, w3.z, az); aw = fmaf(xv.w, w3.w, aw);
        }
        __half2 ha = __floats2half2_rn(ax * dn, ay * dn);
        __half2 hb = __floats2half2_rn(az * dn, aw * dn);
        __half2* dst2 = reinterpret_cast<__half2*>(h1h + (size_t)row * 64 + f4);
        dst2[0] = ha;
        dst2[1] = hb;
    }
}

// ------------- layer-1 gather: wave per node, tail-free padded rows (pad index = N
// -> zero row). 4 features/lane, 16-edge chunks, 4 rows/lane in flight; packed fp16
// tree-add per chunk + one fp32 flush.
__global__ void k_gather1(const int* __restrict__ row_start, const int* __restrict__ cnt,
                          const int* __restrict__ csr, const float* __restrict__ dinv,
                          const __half* __restrict__ h1h, const float* __restrict__ b1,
                          const float* __restrict__ W2, float* __restrict__ h2s, int N) {
    int gtid = blockIdx.x * blockDim.x + threadIdx.x;
    int wid = gtid >> 6, lane = gtid & 63;
    int nwaves = (gridDim.x * blockDim.x) >> 6;
    int q = lane >> 4;                       // edge-slot group [0,4)
    int f = lane & 15;                       // feature quad: features 4f..4f+3
    float4 w2r0 = reinterpret_cast<const float4*>(W2)[4 * f + 0];
    float4 w2r1 = reinterpret_cast<const float4*>(W2)[4 * f + 1];
    float4 w2r2 = reinterpret_cast<const float4*>(W2)[4 * f + 2];
    float4 w2r3 = reinterpret_cast<const float4*>(W2)[4 * f + 3];
    float4 bl4  = reinterpret_cast<const float4*>(b1)[f];
    const uint2* h1v = reinterpret_cast<const uint2*>(h1h);   // row = 16 x uint2 (8B)
    for (int node = wid; node < N; node += nwaves) {
        int rc = cnt[node];
        int rp = (rc + 15) & ~15;            // padded count: loop is tail-free
        int rs = row_start[node];            // 16-aligned
        float dn = dinv[node];
        float a0 = 0.f, a1 = 0.f, a2 = 0.f, a3 = 0.f;
        if (q == 0) {                        // self-loop term once (fp32 path)
            uint2 u = h1v[(size_t)node * 16 + f];
            float2 fa = __half22float2(*reinterpret_cast<__half2*>(&u.x));
            float2 fb = __half22float2(*reinterpret_cast<__half2*>(&u.y));
            a0 = fa.x; a1 = fa.y; a2 = fb.x; a3 = fb.y;
        }
        for (int m = 0; m < rp; m += 16) {   // 4 rows/lane in flight, 16/wave
            int4 cc = *reinterpret_cast<const int4*>(csr + rs + m + q * 4);
            uint2 u0 = h1v[(size_t)cc.x * 16 + f];
            uint2 u1 = h1v[(size_t)cc.y * 16 + f];
            uint2 u2 = h1v[(size_t)cc.z * 16 + f];
            uint2 u3 = h1v[(size_t)cc.w * 16 + f];
            __half2 sx = __hadd2(__hadd2(*reinterpret_cast<__half2*>(&u0.x),
                                         *reinterpret_cast<__half2*>(&u1.x)),
                                 __hadd2(*reinterpret_cast<__half2*>(&u2.x),
                                         *reinterpret_cast<__half2*>(&u3.x)));
            __half2 sy = __hadd2(__hadd2(*reinterpret_cast<__half2*>(&u0.y),
                                         *reinterpret_cast<__half2*>(&u1.y)),
                                 __hadd2(*reinterpret_cast<__half2*>(&u2.y),
                                         *reinterpret_cast<__half2*>(&u3.y)));
            float2 fx = __half22float2(sx);
            float2 fy = __half22float2(sy);
            a0 += fx.x; a1 += fx.y; a2 += fy.x; a3 += fy.y;
        }
        // reduce over the 4 edge-slot groups (bits 4,5 of lane)
        a0 += __shfl_xor(a0, 16); a0 += __shfl_xor(a0, 32);
        a1 += __shfl_xor(a1, 16); a1 += __shfl_xor(a1, 32);
        a2 += __shfl_xor(a2, 16); a2 += __shfl_xor(a2, 32);
        a3 += __shfl_xor(a3, 16); a3 += __shfl_xor(a3, 32);
        float v0 = fmaf(dn, a0, bl4.x);
        float v1 = fmaf(dn, a1, bl4.y);
        float v2 = fmaf(dn, a2, bl4.z);
        float v3 = fmaf(dn, a3, bl4.w);
        v0 = v0 > 0.f ? v0 : 0.01f * v0;     // leaky_relu(0.01)
        v1 = v1 > 0.f ? v1 : 0.01f * v1;
        v2 = v2 > 0.f ? v2 : 0.01f * v2;
        v3 = v3 > 0.f ? v3 : 0.01f * v3;
        float px = v0 * w2r0.x + v1 * w2r1.x + v2 * w2r2.x + v3 * w2r3.x;
        float py = v0 * w2r0.y + v1 * w2r1.y + v2 * w2r2.y + v3 * w2r3.y;
        float pz = v0 * w2r0.z + v1 * w2r1.z + v2 * w2r2.z + v3 * w2r3.z;
        float pw = v0 * w2r0.w + v1 * w2r1.w + v2 * w2r2.w + v3 * w2r3.w;
        #pragma unroll
        for (int off = 8; off >= 1; off >>= 1) {  // reduce over the 16 feature quads
            px += __shfl_xor(px, off);
            py += __shfl_xor(py, off);
            pz += __shfl_xor(pz, off);
            pw += __shfl_xor(pw, off);
        }
        if (lane == 0)
            reinterpret_cast<float4*>(h2s)[node] =
                make_float4(px * dn, py * dn, pz * dn, pw * dn);   // pre-scale by dinv
    }
}

// ------------- layer-2 gather + b2 + softmax -> out [N,4], 16 lanes per node
__global__ void k_gather2(const int* __restrict__ row_start, const int* __restrict__ cnt,
                          const int* __restrict__ csr, const float* __restrict__ dinv,
                          const float* __restrict__ h2s, const float* __restrict__ b2,
                          float* __restrict__ out, int N) {
    int gtid = blockIdx.x * blockDim.x + threadIdx.x;
    int wid = gtid >> 6, lane = gtid & 63;
    int grp = lane >> 4, l = lane & 15;
    int nslots = ((gridDim.x * blockDim.x) >> 6) * 4;
    float b0 = b2[0], b1v = b2[1], b2v = b2[2], b3 = b2[3];
    for (int node = wid * 4 + grp; node < N; node += nslots) {
        int rc = cnt[node];
        int rs = row_start[node];
        float a0 = 0.f, a1 = 0.f, a2 = 0.f, a3 = 0.f;
        for (int k = l; k < rc; k += 16) {
            int s = csr[rs + k];
            float4 hv = reinterpret_cast<const float4*>(h2s)[s];
            a0 += hv.x; a1 += hv.y; a2 += hv.z; a3 += hv.w;
        }
        #pragma unroll
        for (int off = 1; off <= 8; off <<= 1) {
            a0 += __shfl_xor(a0, off);
            a1 += __shfl_xor(a1, off);
            a2 += __shfl_xor(a2, off);
            a3 += __shfl_xor(a3, off);
        }
        if (l == 0) {
            float dn = dinv[node];
            float4 hs = reinterpret_cast<const float4*>(h2s)[node];  // self-loop
            float v0 = fmaf(dn, a0 + hs.x, b0);
            float v1 = fmaf(dn, a1 + hs.y, b1v);
            float v2 = fmaf(dn, a2 + hs.z, b2v);
            float v3 = fmaf(dn, a3 + hs.w, b3);
            float m = fmaxf(fmaxf(v0, v1), fmaxf(v2, v3));
            float e0 = __expf(v0 - m), e1 = __expf(v1 - m);
            float e2 = __expf(v2 - m), e3 = __expf(v3 - m);
            float s = 1.0f / (e0 + e1 + e2 + e3);
            reinterpret_cast<float4*>(out)[node] = make_float4(e0 * s, e1 * s, e2 * s, e3 * s);
        }
    }
}

// ----------------------------------------------------------------
extern "C" void kernel_launch(void* const* d_in, const int* in_sizes, int n_in,
                              void* d_out, int out_size, void* d_ws, size_t ws_size,
                              hipStream_t stream) {
    const float* x  = (const float*)d_in[0];
    const float* W1 = (const float*)d_in[1];
    const float* b1 = (const float*)d_in[2];
    const float* W2 = (const float*)d_in[3];
    const float* b2 = (const float*)d_in[4];
    const int*   ei = (const int*)d_in[5];

    const int N = in_sizes[0] / 128;
    const int E = in_sizes[5] / 2;
    const int* src = ei;
    const int* dst = ei + E;

    const int NBKT = (N + 255) / 256;        // 391 buckets for N=100000

    char* w = (char*)d_ws;
    int*    cnt        = (int*)w;            w += (size_t)N * 4;
    int*    row_start  = (int*)w;            w += (size_t)N * 4;
    int*    pair_cur   = (int*)w;            w += MAXBKT * 4;   // pair_cur + alloc contiguous
    int*    alloc      = (int*)w;            w += 128;
    float*  dinv       = (float*)w;          w += (size_t)N * 4;
    __half* h1h        = (__half*)w;         w += (size_t)N * 64 * 4;  // (N+1) fp16 rows fit the slot
    float*  h2s        = (float*)w;          w += (size_t)N * 4 * 4;
    int*    csr        = (int*)w;            // (E + 15N) * 4 bytes worst case
    int*    pairs      = (int*)h1h;          // alias (NBKT*BKT_CAP*4 = 25.0 MB <= 25.6 MB slot)

    hipMemsetAsync(pair_cur, 0, MAXBKT * 4 + 128, stream);     // cursors + allocator
    k_partition<<<512, P_TPB, 0, stream>>>(src, dst, pair_cur, pairs, E, NBKT);
    k_bucket_build<<<NBKT, B_TPB, 0, stream>>>(pair_cur, pairs, alloc, cnt, row_start,
                                               dinv, csr, N);
    k_gemm1<<<2048, TPB, 0, stream>>>(x, W1, dinv, h1h, N);   // pairs consumed; zeroes row N
    k_gather1<<<2048, TPB, 0, stream>>>(row_start, cnt, csr, dinv, h1h, b1, W2, h2s, N);
    k_gather2<<<2048, TPB, 0, stream>>>(row_start, cnt, csr, dinv, h2s, b2, (float*)d_out, N);
}

// Round 22
// 173.925 us; speedup vs baseline: 1.0442x; 1.0442x over previous
//
#include <hip/hip_runtime.h>
#include <hip/hip_fp16.h>
#include <cstddef>

static constexpr int TPB = 256;
static constexpr int TPB_BIG = 1024;         // build kernels: max TLP
// bucket = 256 consecutive dst nodes (shift 8); NBKT = ceil(N/256) <= 512
static constexpr int MAXBKT = 512;
// fixed pairs region per bucket; mean bucket load = 8192, sigma ~ 90 -> 16000 is ~86 sigma
static constexpr int BKT_CAP = 16000;

// single pass: partition edges into fixed per-bucket regions; per-(block,bucket)
// private contiguous sub-ranges via one global atomic per bucket. entry=(s<<8)|(d&255).
// 256 blocks x 1024 thr: 32-entry (128B) runs keep lines mostly-full (512 blocks
// halved runs to unaligned 64B -> 2x write amplification, R20 regression).
__global__ __launch_bounds__(TPB_BIG) void k_partition(const int* __restrict__ src,
                                                       const int* __restrict__ dst,
                                                       int* __restrict__ pair_cur,
                                                       int* __restrict__ pairs, int E, int nbkt) {
    __shared__ int hist[MAXBKT];
    __shared__ int base[MAXBKT];
    const int chunk = (E + gridDim.x - 1) / gridDim.x;
    const int e0 = blockIdx.x * chunk;
    const int e1 = min(e0 + chunk, E);
    for (int b = threadIdx.x; b < nbkt; b += TPB_BIG) hist[b] = 0;
    __syncthreads();
    for (int e = e0 + threadIdx.x; e < e1; e += TPB_BIG)
        atomicAdd(&hist[dst[e] >> 8], 1);
    __syncthreads();
    for (int b = threadIdx.x; b < nbkt; b += TPB_BIG) {
        int h = hist[b];
        base[b] = b * BKT_CAP + (h ? atomicAdd(&pair_cur[b], h) : 0);
    }
    __syncthreads();
    for (int e = e0 + threadIdx.x; e < e1; e += TPB_BIG) {
        int s = src[e], d = dst[e];
        int slot = atomicAdd(&base[d >> 8], 1);
        pairs[slot] = (s << 8) | (d & 255);    // s < 2^17 -> fits
    }
}

// fused CSR build: one block per bucket, 1024 threads (R20: 2x TLP on both pairs
// scans cut this kernel ~30us). LDS hist -> cnt/dinv; padded local scan; global
// base via atomic allocator; LDS-cursor scatter; pad slots filled with dummy
// index N (zero row) so the gather loop needs no tail.
__global__ __launch_bounds__(TPB_BIG) void k_bucket_build(const int* __restrict__ pair_cur,
                                                          const int* __restrict__ pairs,
                                                          int* __restrict__ alloc,
                                                          int* __restrict__ cnt,
                                                          int* __restrict__ row_start,
                                                          float* __restrict__ dinv,
                                                          int* __restrict__ csr, int N) {
    __shared__ int c[256];
    __shared__ int cur[256];
    __shared__ int wsum[4];
    __shared__ int base_s;
    int b = blockIdx.x;
    int tid = threadIdx.x;
    int lo = b * BKT_CAP, hi = lo + pair_cur[b];
    if (tid < 256) c[tid] = 0;
    __syncthreads();
    for (int k = lo + tid; k < hi; k += TPB_BIG)
        atomicAdd(&c[pairs[k] & 255], 1);
    __syncthreads();
    int node = (b << 8) + tid;
    int cc = 0, p = 0, excl = 0;
    if (tid < 256) {
        cc = c[tid];
        p = (node < N) ? ((cc + 15) & ~15) : 0;
        int lane = tid & 63, w = tid >> 6;
        int v = p;
        #pragma unroll
        for (int off = 1; off < 64; off <<= 1) {
            int u = __shfl_up(v, off);
            if (lane >= off) v += u;
        }
        if (lane == 63) wsum[w] = v;
        excl = v - p;                        // within-wave exclusive (add woff later)
    }
    __syncthreads();
    if (tid == 0) {
        int total = wsum[0] + wsum[1] + wsum[2] + wsum[3];
        base_s = atomicAdd(alloc, total);
    }
    __syncthreads();
    if (tid < 256 && node < N) {
        int w = tid >> 6;
        int woff = 0;
        for (int i = 0; i < w; ++i) woff += wsum[i];
        int rs = base_s + woff + excl;
        row_start[node] = rs;
        cnt[node] = cc;
        dinv[node] = rsqrtf(1.0f + (float)cc);   // deg = cnt + 1 (self-loop)
        cur[tid] = rs;
    }
    __syncthreads();
    for (int k = lo + tid; k < hi; k += TPB_BIG) {
        int pp = pairs[k];
        int slot = atomicAdd(&cur[pp & 255], 1);
        csr[slot] = pp >> 8;
    }
    __syncthreads();
    if (tid < 256 && node < N) {             // fill pad slots with dummy index N
        int end = row_start[node] + ((cc + 15) & ~15);
        for (int j = cur[tid]; j < end; ++j) csr[j] = N;
    }
}

// -------------------- h1h = fp16( dinv * (x @ W1) )   [N,128]x[128,64], row-scaled
// quarter-wave per row: lane&15 selects 4 consecutive features, lane>>4 selects row in quad.
// Block 0 also zeroes the dummy row N -- AFTER pairs (which aliases h1h) was consumed
// by k_bucket_build, and before k_gather1 reads it (stream order).
__global__ __launch_bounds__(TPB) void k_gemm1(const float* __restrict__ x,
                                               const float* __restrict__ W1,
                                               const float* __restrict__ dinv,
                                               __half* __restrict__ h1h, int N) {
    if (blockIdx.x == 0 && threadIdx.x < 32)
        reinterpret_cast<int*>(h1h)[(size_t)N * 32 + threadIdx.x] = 0;
    __shared__ float W1s[128 * 64];          // 32 KB
    {
        const float4* W1v = reinterpret_cast<const float4*>(W1);
        float4* W1sv = reinterpret_cast<float4*>(W1s);
        for (int i = threadIdx.x; i < 128 * 64 / 4; i += TPB) W1sv[i] = W1v[i];
    }
    __syncthreads();
    const int lane = threadIdx.x & 63;
    const int wid  = threadIdx.x >> 6;       // 4 waves
    const int q    = lane >> 4;              // row within quad
    const int f4   = (lane & 15) * 4;        // feature base
    for (int rb = blockIdx.x * 16 + wid * 4; rb < N; rb += gridDim.x * 16) {
        int row = rb + q;
        const float4* xr4 = reinterpret_cast<const float4*>(x + (size_t)row * 128);
        float dn = dinv[row];
        float ax = 0.f, ay = 0.f, az = 0.f, aw = 0.f;
        #pragma unroll 8
        for (int k4 = 0; k4 < 32; ++k4) {
            float4 xv = xr4[k4];             // quarter-uniform broadcast load
            const float4* wrow = reinterpret_cast<const float4*>(&W1s[(k4 * 4) * 64 + f4]);
            float4 w0 = wrow[0];
            float4 w1 = wrow[16];            // next k: +64 floats = +16 float4
            float4 w2 = wrow[32];
            float4 w3 = wrow[48];
            ax = fmaf(xv.x, w0.x, ax); ay = fmaf(xv.x, w0.y, ay);
            az = fmaf(xv.x, w0.z, az); aw = fmaf(xv.x, w0.w, aw);
            ax = fmaf(xv.y, w1.x, ax); ay = fmaf(xv.y, w1.y, ay);
            az = fmaf(xv.y, w1.z, az); aw = fmaf(xv.y, w1.w, aw);
            ax = fmaf(xv.z, w2.x, ax); ay = fmaf(xv.z, w2.y, ay);
            az = fmaf(xv.z, w2.z, az); aw = fmaf(xv.z, w2.w, aw);
            ax = fmaf(xv.w, w3.x, ax); ay = fmaf(xv.w, w3.y, ay);
            az = fmaf(xv.w, w3.z, az); aw = fmaf(xv.w, w3.w, aw);
        }
        __half2 ha = __floats2half2_rn(ax * dn, ay * dn);
        __half2 hb = __floats2half2_rn(az * dn, aw * dn);
        __half2* dst2 = reinterpret_cast<__half2*>(h1h + (size_t)row * 64 + f4);
        dst2[0] = ha;
        dst2[1] = hb;
    }
}

// ------------- layer-1 gather: wave per node, tail-free padded rows (pad index = N
// -> zero row). 4 features/lane, 16-edge chunks, 4 rows/lane in flight; packed fp16
// tree-add per chunk + one fp32 flush.
__global__ void k_gather1(const int* __restrict__ row_start, const int* __restrict__ cnt,
                          const int* __restrict__ csr, const float* __restrict__ dinv,
                          const __half* __restrict__ h1h, const float* __restrict__ b1,
                          const float* __restrict__ W2, float* __restrict__ h2s, int N) {
    int gtid = blockIdx.x * blockDim.x + threadIdx.x;
    int wid = gtid >> 6, lane = gtid & 63;
    int nwaves = (gridDim.x * blockDim.x) >> 6;
    int q = lane >> 4;                       // edge-slot group [0,4)
    int f = lane & 15;                       // feature quad: features 4f..4f+3
    float4 w2r0 = reinterpret_cast<const float4*>(W2)[4 * f + 0];
    float4 w2r1 = reinterpret_cast<const float4*>(W2)[4 * f + 1];
    float4 w2r2 = reinterpret_cast<const float4*>(W2)[4 * f + 2];
    float4 w2r3 = reinterpret_cast<const float4*>(W2)[4 * f + 3];
    float4 bl4  = reinterpret_cast<const float4*>(b1)[f];
    const uint2* h1v = reinterpret_cast<const uint2*>(h1h);   // row = 16 x uint2 (8B)
    for (int node = wid; node < N; node += nwaves) {
        int rc = cnt[node];
        int rp = (rc + 15) & ~15;            // padded count: loop is tail-free
        int rs = row_start[node];            // 16-aligned
        float dn = dinv[node];
        float a0 = 0.f, a1 = 0.f, a2 = 0.f, a3 = 0.f;
        if (q == 0) {                        // self-loop term once (fp32 path)
            uint2 u = h1v[(size_t)node * 16 + f];
            float2 fa = __half22float2(*reinterpret_cast<__half2*>(&u.x));
            float2 fb = __half22float2(*reinterpret_cast<__half2*>(&u.y));
            a0 = fa.x; a1 = fa.y; a2 = fb.x; a3 = fb.y;
        }
        for (int m = 0; m < rp; m += 16) {   // 4 rows/lane in flight, 16/wave
            int4 cc = *reinterpret_cast<const int4*>(csr + rs + m + q * 4);
            uint2 u0 = h1v[(size_t)cc.x * 16 + f];
            uint2 u1 = h1v[(size_t)cc.y * 16 + f];
            uint2 u2 = h1v[(size_t)cc.z * 16 + f];
            uint2 u3 = h1v[(size_t)cc.w * 16 + f];
            __half2 sx = __hadd2(__hadd2(*reinterpret_cast<__half2*>(&u0.x),
                                         *reinterpret_cast<__half2*>(&u1.x)),
                                 __hadd2(*reinterpret_cast<__half2*>(&u2.x),
                                         *reinterpret_cast<__half2*>(&u3.x)));
            __half2 sy = __hadd2(__hadd2(*reinterpret_cast<__half2*>(&u0.y),
                                         *reinterpret_cast<__half2*>(&u1.y)),
                                 __hadd2(*reinterpret_cast<__half2*>(&u2.y),
                                         *reinterpret_cast<__half2*>(&u3.y)));
            float2 fx = __half22float2(sx);
            float2 fy = __half22float2(sy);
            a0 += fx.x; a1 += fx.y; a2 += fy.x; a3 += fy.y;
        }
        // reduce over the 4 edge-slot groups (bits 4,5 of lane)
        a0 += __shfl_xor(a0, 16); a0 += __shfl_xor(a0, 32);
        a1 += __shfl_xor(a1, 16); a1 += __shfl_xor(a1, 32);
        a2 += __shfl_xor(a2, 16); a2 += __shfl_xor(a2, 32);
        a3 += __shfl_xor(a3, 16); a3 += __shfl_xor(a3, 32);
        float v0 = fmaf(dn, a0, bl4.x);
        float v1 = fmaf(dn, a1, bl4.y);
        float v2 = fmaf(dn, a2, bl4.z);
        float v3 = fmaf(dn, a3, bl4.w);
        v0 = v0 > 0.f ? v0 : 0.01f * v0;     // leaky_relu(0.01)
        v1 = v1 > 0.f ? v1 : 0.01f * v1;
        v2 = v2 > 0.f ? v2 : 0.01f * v2;
        v3 = v3 > 0.f ? v3 : 0.01f * v3;
        float px = v0 * w2r0.x + v1 * w2r1.x + v2 * w2r2.x + v3 * w2r3.x;
        float py = v0 * w2r0.y + v1 * w2r1.y + v2 * w2r2.y + v3 * w2r3.y;
        float pz = v0 * w2r0.z + v1 * w2r1.z + v2 * w2r2.z + v3 * w2r3.z;
        float pw = v0 * w2r0.w + v1 * w2r1.w + v2 * w2r2.w + v3 * w2r3.w;
        #pragma unroll
        for (int off = 8; off >= 1; off >>= 1) {  // reduce over the 16 feature quads
            px += __shfl_xor(px, off);
            py += __shfl_xor(py, off);
            pz += __shfl_xor(pz, off);
            pw += __shfl_xor(pw, off);
        }
        if (lane == 0)
            reinterpret_cast<float4*>(h2s)[node] =
                make_float4(px * dn, py * dn, pz * dn, pw * dn);   // pre-scale by dinv
    }
}

// ------------- layer-2 gather + b2 + softmax -> out [N,4], 16 lanes per node
__global__ void k_gather2(const int* __restrict__ row_start, const int* __restrict__ cnt,
                          const int* __restrict__ csr, const float* __restrict__ dinv,
                          const float* __restrict__ h2s, const float* __restrict__ b2,
                          float* __restrict__ out, int N) {
    int gtid = blockIdx.x * blockDim.x + threadIdx.x;
    int wid = gtid >> 6, lane = gtid & 63;
    int grp = lane >> 4, l = lane & 15;
    int nslots = ((gridDim.x * blockDim.x) >> 6) * 4;
    float b0 = b2[0], b1v = b2[1], b2v = b2[2], b3 = b2[3];
    for (int node = wid * 4 + grp; node < N; node += nslots) {
        int rc = cnt[node];
        int rs = row_start[node];
        float a0 = 0.f, a1 = 0.f, a2 = 0.f, a3 = 0.f;
        for (int k = l; k < rc; k += 16) {
            int s = csr[rs + k];
            float4 hv = reinterpret_cast<const float4*>(h2s)[s];
            a0 += hv.x; a1 += hv.y; a2 += hv.z; a3 += hv.w;
        }
        #pragma unroll
        for (int off = 1; off <= 8; off <<= 1) {
            a0 += __shfl_xor(a0, off);
            a1 += __shfl_xor(a1, off);
            a2 += __shfl_xor(a2, off);
            a3 += __shfl_xor(a3, off);
        }
        if (l == 0) {
            float dn = dinv[node];
            float4 hs = reinterpret_cast<const float4*>(h2s)[node];  // self-loop
            float v0 = fmaf(dn, a0 + hs.x, b0);
            float v1 = fmaf(dn, a1 + hs.y, b1v);
            float v2 = fmaf(dn, a2 + hs.z, b2v);
            float v3 = fmaf(dn, a3 + hs.w, b3);
            float m = fmaxf(fmaxf(v0, v1), fmaxf(v2, v3));
            float e0 = __expf(v0 - m), e1 = __expf(v1 - m);
            float e2 = __expf(v2 - m), e3 = __expf(v3 - m);
            float s = 1.0f / (e0 + e1 + e2 + e3);
            reinterpret_cast<float4*>(out)[node] = make_float4(e0 * s, e1 * s, e2 * s, e3 * s);
        }
    }
}

// ----------------------------------------------------------------
extern "C" void kernel_launch(void* const* d_in, const int* in_sizes, int n_in,
                              void* d_out, int out_size, void* d_ws, size_t ws_size,
                              hipStream_t stream) {
    const float* x  = (const float*)d_in[0];
    const float* W1 = (const float*)d_in[1];
    const float* b1 = (const float*)d_in[2];
    const float* W2 = (const float*)d_in[3];
    const float* b2 = (const float*)d_in[4];
    const int*   ei = (const int*)d_in[5];

    const int N = in_sizes[0] / 128;
    const int E = in_sizes[5] / 2;
    const int* src = ei;
    const int* dst = ei + E;

    const int NBKT = (N + 255) / 256;        // 391 buckets for N=100000

    char* w = (char*)d_ws;
    int*    cnt        = (int*)w;            w += (size_t)N * 4;
    int*    row_start  = (int*)w;            w += (size_t)N * 4;
    int*    pair_cur   = (int*)w;            w += MAXBKT * 4;   // pair_cur + alloc contiguous
    int*    alloc      = (int*)w;            w += 128;
    float*  dinv       = (float*)w;          w += (size_t)N * 4;
    __half* h1h        = (__half*)w;         w += (size_t)N * 64 * 4;  // (N+1) fp16 rows fit the slot
    float*  h2s        = (float*)w;          w += (size_t)N * 4 * 4;
    int*    csr        = (int*)w;            // (E + 15N) * 4 bytes worst case
    int*    pairs      = (int*)h1h;          // alias (NBKT*BKT_CAP*4 = 25.0 MB <= 25.6 MB slot)

    hipMemsetAsync(pair_cur, 0, MAXBKT * 4 + 128, stream);     // cursors + allocator
    k_partition<<<256, TPB_BIG, 0, stream>>>(src, dst, pair_cur, pairs, E, NBKT);
    k_bucket_build<<<NBKT, TPB_BIG, 0, stream>>>(pair_cur, pairs, alloc, cnt, row_start,
                                                 dinv, csr, N);
    k_gemm1<<<2048, TPB, 0, stream>>>(x, W1, dinv, h1h, N);   // pairs consumed; zeroes row N
    k_gather1<<<2048, TPB, 0, stream>>>(row_start, cnt, csr, dinv, h1h, b1, W2, h2s, N);
    k_gather2<<<2048, TPB, 0, stream>>>(row_start, cnt, csr, dinv, h2s, b2, (float*)d_out, N);
}